// Round 1
// baseline (86.850 us; speedup 1.0000x reference)
//
#include <hip/hip_runtime.h>
#include <cstdint>
#include <cmath>

// QuantumLatentLayer: out[b,q] = cos(a)*cos(theta_q) - sin(a)*(cos(phi_q)*sin(theta_q))
//                     a = sum_l latent[b,l]*W[q,l] + b_q
// M=32768 rows, K=2048, N=24 qubits. Memory-bound: 268 MB latent stream @ ~6.3 TB/s -> ~43 us floor.

#define NQ 24
#define LDIM 2048
#define BATCH 32768
#define KC 32            // k-chunk (floats) staged per buffer
#define ROWS 64          // rows per wave tile
#define BLK_ROWS 128     // rows per block (2 row-halves)
#define KSPAN 1024       // k range per k-half (2-way k split)
#define NCHUNK (KSPAN / KC)   // 32 chunks per wave

typedef const __attribute__((address_space(1))) void* gas_t;
typedef __attribute__((address_space(3))) void* las_t;

__device__ __forceinline__ void gload_lds16(const float* g, float* l) {
    // async global->LDS, 16B/lane; LDS dest = wave-uniform base + lane*16
    __builtin_amdgcn_global_load_lds((gas_t)g, (las_t)l, 16, 0, 0);
}

// Stage latent tile [64 rows][KC=32 floats] with XOR-swizzled SOURCE so that the
// linear LDS layout holds a (slot ^= row&7)-swizzled tile (m173 pattern).
// 8 insts x 1024B; inst i covers rows 8i..8i+7 (128B each = 8 slots of 16B).
__device__ __forceinline__ void stage_lat(const float* src /* latent + rowbase*LDIM + k */,
                                          float* ldst, int lane) {
    const int swz = (((lane & 7) ^ ((lane >> 3) & 7)) << 2); // float offset within 32-float row
    const int rsub = lane >> 3;
    #pragma unroll
    for (int i = 0; i < 8; i++) {
        const float* g = src + (size_t)(i * 8 + rsub) * LDIM + swz;
        gload_lds16(g, ldst + i * 256);
    }
}

// Stage Wt chunk [KC=32 k][24 q] = 3072B contiguous, linear. 3 insts.
__device__ __forceinline__ void stage_w(const float* wsrc /* wt + k*NQ */, float* wdst, int lane) {
    #pragma unroll
    for (int i = 0; i < 3; i++)
        gload_lds16(wsrc + i * 256 + lane * 4, wdst + i * 256);
}

// Per lane: rows {p, p+32}, qubits [12h, 12h+12). 768 FMA per chunk.
__device__ __forceinline__ void compute_chunk(const float* __restrict__ lbuf,
                                              const float* __restrict__ wbuf,
                                              int p, int h, float (&acc)[2][12]) {
    const int r0 = p, r1 = p + 32;
    const int sw = (p & 7) << 2;   // same for p and p+32
    #pragma unroll
    for (int s = 0; s < KC; s += 4) {
        float4 la = *(const float4*)(lbuf + r0 * KC + (s ^ sw));
        float4 lb = *(const float4*)(lbuf + r1 * KC + (s ^ sw));
        #pragma unroll
        for (int j = 0; j < 4; j++) {
            const float* wp = wbuf + (s + j) * NQ + h * 12;
            float4 w0 = *(const float4*)(wp + 0);
            float4 w1 = *(const float4*)(wp + 4);
            float4 w2 = *(const float4*)(wp + 8);
            float wv[12] = {w0.x, w0.y, w0.z, w0.w, w1.x, w1.y, w1.z, w1.w,
                            w2.x, w2.y, w2.z, w2.w};
            float a0 = ((const float*)&la)[j];
            float a1 = ((const float*)&lb)[j];
            #pragma unroll
            for (int t = 0; t < 12; t++) {
                acc[0][t] = fmaf(a0, wv[t], acc[0][t]);
                acc[1][t] = fmaf(a1, wv[t], acc[1][t]);
            }
        }
    }
}

__global__ __launch_bounds__(256, 1) void qll_main(
    const float* __restrict__ latent,
    const float* __restrict__ wt,    // [LDIM][NQ] transposed W
    const float* __restrict__ bvec,  // [NQ]
    const float* __restrict__ ctv,   // [NQ] cos(theta)
    const float* __restrict__ csv,   // [NQ] cos(phi)*sin(theta)
    float* __restrict__ out)
{
    __shared__ __align__(16) float lat_lds[4][2][ROWS * KC];  // 64 KB
    __shared__ __align__(16) float w_lds[4][2][KC * NQ];      // 24 KB
    __shared__ __align__(16) float red[2][BLK_ROWS][NQ];      // 24 KB

    const int tid  = threadIdx.x;
    const int wave = tid >> 6;
    const int lane = tid & 63;
    const int kh   = wave >> 1;       // k-half 0..1
    const int rh   = wave & 1;        // row-half 0..1
    const int p    = lane & 31;
    const int h    = lane >> 5;

    const int row0 = blockIdx.x * BLK_ROWS + rh * ROWS;
    const int k0   = kh * KSPAN;

    const float* lsrc = latent + (size_t)row0 * LDIM + k0;
    const float* wsrc = wt + (size_t)k0 * NQ;

    float* lb0 = &lat_lds[wave][0][0];
    float* lb1 = &lat_lds[wave][1][0];
    float* wb0 = &w_lds[wave][0][0];
    float* wb1 = &w_lds[wave][1][0];

    float acc[2][12];
    #pragma unroll
    for (int g = 0; g < 2; g++)
        #pragma unroll
        for (int t = 0; t < 12; t++) acc[g][t] = 0.0f;

    // prologue: stage chunk 0 into buffer 0 (11 VMEM insts)
    stage_lat(lsrc, lb0, lane);
    stage_w(wsrc, wb0, lane);

    #pragma unroll 1
    for (int c = 0; c < NCHUNK; c++) {
        if (c + 1 < NCHUNK) {
            if ((c & 1) == 0) {
                stage_lat(lsrc + (c + 1) * KC, lb1, lane);
                stage_w(wsrc + (size_t)(c + 1) * KC * NQ, wb1, lane);
            } else {
                stage_lat(lsrc + (c + 1) * KC, lb0, lane);
                stage_w(wsrc + (size_t)(c + 1) * KC * NQ, wb0, lane);
            }
            // current chunk's 11 loads done; next chunk's 11 stay in flight
            asm volatile("s_waitcnt vmcnt(11)" ::: "memory");
        } else {
            asm volatile("s_waitcnt vmcnt(0)" ::: "memory");
        }
        if ((c & 1) == 0) compute_chunk(lb0, wb0, p, h, acc);
        else              compute_chunk(lb1, wb1, p, h, acc);
    }

    // write k-half partials: red[kh][rowInBlock][q]
    {
        float* r0p = &red[kh][rh * ROWS + p][h * 12];
        float* r1p = &red[kh][rh * ROWS + p + 32][h * 12];
        #pragma unroll
        for (int v = 0; v < 3; v++) {
            ((float4*)r0p)[v] = make_float4(acc[0][4*v], acc[0][4*v+1], acc[0][4*v+2], acc[0][4*v+3]);
            ((float4*)r1p)[v] = make_float4(acc[1][4*v], acc[1][4*v+1], acc[1][4*v+2], acc[1][4*v+3]);
        }
    }
    __syncthreads();

    // epilogue: 128 rows x 24 q = 3072 outputs, 12 per thread, coalesced stores
    const size_t outbase = (size_t)blockIdx.x * BLK_ROWS * NQ;
    #pragma unroll
    for (int i = 0; i < 12; i++) {
        int flat = i * 256 + tid;
        int r = flat / NQ;
        int q = flat - r * NQ;
        float a = red[0][r][q] + red[1][r][q] + bvec[q];
        float s, co;
        __sincosf(a, &s, &co);
        out[outbase + flat] = co * ctv[q] - s * csv[q];
    }
}

// Prep: Wt[k][q] = W[q][k]; ctcs[0..23]=cos(theta), ctcs[24..47]=cos(phi)*sin(theta)
__global__ __launch_bounds__(256) void qll_prep(
    const float* __restrict__ W, const float* __restrict__ params,
    float* __restrict__ wt, float* __restrict__ ctcs)
{
    int idx = blockIdx.x * 256 + threadIdx.x;
    if (idx < LDIM * NQ) {
        int q = idx % NQ;
        int k = idx / NQ;
        wt[idx] = W[q * LDIM + k];
    }
    if (idx < NQ) {
        float phi = params[3 * idx + 0];
        float th  = params[3 * idx + 1];
        ctcs[idx]      = cosf(th);
        ctcs[NQ + idx] = cosf(phi) * sinf(th);
    }
}

extern "C" void kernel_launch(void* const* d_in, const int* in_sizes, int n_in,
                              void* d_out, int out_size, void* d_ws, size_t ws_size,
                              hipStream_t stream) {
    (void)in_sizes; (void)n_in; (void)out_size; (void)ws_size;
    const float* latent = (const float*)d_in[0];
    const float* W      = (const float*)d_in[1];
    const float* bvec   = (const float*)d_in[2];
    const float* params = (const float*)d_in[3];
    float* out  = (float*)d_out;
    float* wt   = (float*)d_ws;              // LDIM*NQ floats
    float* ctcs = wt + LDIM * NQ;            // 2*NQ floats

    hipLaunchKernelGGL(qll_prep, dim3((LDIM * NQ + 255) / 256), dim3(256), 0, stream,
                       W, params, wt, ctcs);
    hipLaunchKernelGGL(qll_main, dim3(BATCH / BLK_ROWS), dim3(256), 0, stream,
                       latent, wt, bvec, ctcs, ctcs + NQ, out);
}

// Round 2
// 73.902 us; speedup vs baseline: 1.1752x; 1.1752x over previous
//
#include <hip/hip_runtime.h>
#include <cstdint>
#include <cmath>

// QuantumLatentLayer: out[b,q] = cos(a)*cos(theta_q) - sin(a)*(cos(phi_q)*sin(theta_q))
//                     a = sum_l latent[b,l]*W[q,l] + b_q
// M=32768, K=2048, N=24. HBM floor ~39 us @ 7 TB/s (fills measured 7.0 TB/s).
// R1 lesson: W ds_read broadcasts cost full DS-pipe price -> amortize W reads
// over R=4 rows/lane (8 DS insts per KB of latent instead of 14).

#define NQ 24
#define LDIM 2048
#define BATCH 32768
#define KC 32             // k-chunk (floats) per buffer
#define BLK_ROWS 128      // rows per block; wave covers all 128
#define KSPAN 512         // k range per wave (4-way k split)
#define NCHUNK (KSPAN / KC)   // 16 chunks

typedef const __attribute__((address_space(1))) void* gas_t;
typedef __attribute__((address_space(3))) void* las_t;

__device__ __forceinline__ void gload_lds16(const float* g, float* l) {
    __builtin_amdgcn_global_load_lds((gas_t)g, (las_t)l, 16, 0, 0);
}

// Stage latent tile [128 rows][KC=32 floats], XOR-swizzled SOURCE (m173): the
// linear LDS tile holds slot s of row r at s^(r&7). 16 insts x 1024 B.
__device__ __forceinline__ void stage_lat(const float* src, float* ldst, int lane) {
    const int swz  = (((lane & 7) ^ ((lane >> 3) & 7)) << 2); // float offset in 32-float row
    const int rsub = lane >> 3;
    #pragma unroll
    for (int i = 0; i < 16; i++) {
        const float* g = src + (size_t)(i * 8 + rsub) * LDIM + swz;
        gload_lds16(g, ldst + i * 256);
    }
}

// Stage Wt chunk [KC=32 k][24 q] = 3072 B contiguous, linear. 3 insts.
__device__ __forceinline__ void stage_w(const float* wsrc, float* wdst, int lane) {
    #pragma unroll
    for (int i = 0; i < 3; i++)
        gload_lds16(wsrc + i * 256 + lane * 4, wdst + i * 256);
}

// Lane owns rows {p, p+32, p+64, p+96}, qubits [12h, 12h+12).
// Per chunk: 32 latent + 96 W ds_read_b128, 1536 FMA.
__device__ __forceinline__ void compute_chunk(const float* __restrict__ lbuf,
                                              const float* __restrict__ wbuf,
                                              int p, int h, float (&acc)[4][12]) {
    const int sw = (p & 7) << 2;   // same swizzle for all 4 rows (p+32r keeps r&7)
    #pragma unroll
    for (int s = 0; s < KC; s += 4) {
        float4 lv[4];
        #pragma unroll
        for (int r = 0; r < 4; r++)
            lv[r] = *(const float4*)(lbuf + (p + 32 * r) * KC + (s ^ sw));
        #pragma unroll
        for (int j = 0; j < 4; j++) {
            const float* wp = wbuf + (s + j) * NQ + h * 12;
            float4 w0 = *(const float4*)(wp + 0);
            float4 w1 = *(const float4*)(wp + 4);
            float4 w2 = *(const float4*)(wp + 8);
            float wv[12] = {w0.x, w0.y, w0.z, w0.w, w1.x, w1.y, w1.z, w1.w,
                            w2.x, w2.y, w2.z, w2.w};
            #pragma unroll
            for (int r = 0; r < 4; r++) {
                float a = ((const float*)&lv[r])[j];
                #pragma unroll
                for (int t = 0; t < 12; t++)
                    acc[r][t] = fmaf(a, wv[t], acc[r][t]);
            }
        }
    }
}

__global__ __launch_bounds__(256, 1) void qll_main(
    const float* __restrict__ latent,
    const float* __restrict__ wt,    // [LDIM][NQ]
    const float* __restrict__ bvec,  // [NQ]
    const float* __restrict__ ctv,   // [NQ] cos(theta)
    const float* __restrict__ csv,   // [NQ] cos(phi)*sin(theta)
    float* __restrict__ out)
{
    __shared__ __align__(16) float lat_lds[4][2][BLK_ROWS * KC]; // 128 KB
    __shared__ __align__(16) float w_lds[4][2][KC * NQ];         // 24 KB -> 152 KB total

    const int tid  = threadIdx.x;
    const int wave = tid >> 6;
    const int lane = tid & 63;
    const int p    = lane & 31;
    const int h    = lane >> 5;

    const int row0 = blockIdx.x * BLK_ROWS;
    const int k0   = wave * KSPAN;

    const float* lsrc = latent + (size_t)row0 * LDIM + k0;
    const float* wsrc = wt + (size_t)k0 * NQ;

    float* lb0 = &lat_lds[wave][0][0];
    float* lb1 = &lat_lds[wave][1][0];
    float* wb0 = &w_lds[wave][0][0];
    float* wb1 = &w_lds[wave][1][0];

    float acc[4][12];
    #pragma unroll
    for (int r = 0; r < 4; r++)
        #pragma unroll
        for (int t = 0; t < 12; t++) acc[r][t] = 0.0f;

    // prologue: chunk 0 into buffer 0 (19 VMEM insts)
    stage_lat(lsrc, lb0, lane);
    stage_w(wsrc, wb0, lane);

    #pragma unroll 1
    for (int c = 0; c < NCHUNK; c++) {
        if (c + 1 < NCHUNK) {
            if ((c & 1) == 0) {
                stage_lat(lsrc + (c + 1) * KC, lb1, lane);
                stage_w(wsrc + (size_t)(c + 1) * KC * NQ, wb1, lane);
            } else {
                stage_lat(lsrc + (c + 1) * KC, lb0, lane);
                stage_w(wsrc + (size_t)(c + 1) * KC * NQ, wb0, lane);
            }
            // current chunk's 19 loads complete; next chunk's 19 in flight
            asm volatile("s_waitcnt vmcnt(19)" ::: "memory");
        } else {
            asm volatile("s_waitcnt vmcnt(0)" ::: "memory");
        }
        if ((c & 1) == 0) compute_chunk(lb0, wb0, p, h, acc);
        else              compute_chunk(lb1, wb1, p, h, acc);
    }

    // k-partials: reuse this wave's (now dead) latent buffer 0 as red[128][24]
    {
        float* redw = &lat_lds[wave][0][0];
        #pragma unroll
        for (int r = 0; r < 4; r++) {
            float* dst = redw + (size_t)(p + 32 * r) * NQ + h * 12;
            ((float4*)dst)[0] = make_float4(acc[r][0], acc[r][1], acc[r][2],  acc[r][3]);
            ((float4*)dst)[1] = make_float4(acc[r][4], acc[r][5], acc[r][6],  acc[r][7]);
            ((float4*)dst)[2] = make_float4(acc[r][8], acc[r][9], acc[r][10], acc[r][11]);
        }
    }
    __syncthreads();

    // epilogue: thread owns 12 consecutive outputs [tid*12, tid*12+12).
    // q = (tid&1)*12 + i  (no modulo: tid*12 mod 24 = (tid&1)*12, i<12).
    {
        const int qbase = (tid & 1) * 12;
        const int flat0 = tid * 12;
        const size_t outbase = (size_t)blockIdx.x * (BLK_ROWS * NQ) + flat0;
        #pragma unroll
        for (int v = 0; v < 3; v++) {
            float4 o;
            #pragma unroll
            for (int e = 0; e < 4; e++) {
                int i = v * 4 + e;
                int flat = flat0 + i;
                int q = qbase + i;
                float a = lat_lds[0][0][flat] + lat_lds[1][0][flat]
                        + lat_lds[2][0][flat] + lat_lds[3][0][flat] + bvec[q];
                float s, co;
                __sincosf(a, &s, &co);
                ((float*)&o)[e] = co * ctv[q] - s * csv[q];
            }
            *(float4*)(out + outbase + v * 4) = o;
        }
    }
}

// Prep: Wt[k][q] = W[q][k]; ctcs[0..23]=cos(theta), ctcs[24..47]=cos(phi)*sin(theta)
__global__ __launch_bounds__(256) void qll_prep(
    const float* __restrict__ W, const float* __restrict__ params,
    float* __restrict__ wt, float* __restrict__ ctcs)
{
    int idx = blockIdx.x * 256 + threadIdx.x;
    if (idx < LDIM * NQ) {
        int q = idx % NQ;
        int k = idx / NQ;
        wt[idx] = W[q * LDIM + k];
    }
    if (idx < NQ) {
        float phi = params[3 * idx + 0];
        float th  = params[3 * idx + 1];
        ctcs[idx]      = cosf(th);
        ctcs[NQ + idx] = cosf(phi) * sinf(th);
    }
}

extern "C" void kernel_launch(void* const* d_in, const int* in_sizes, int n_in,
                              void* d_out, int out_size, void* d_ws, size_t ws_size,
                              hipStream_t stream) {
    (void)in_sizes; (void)n_in; (void)out_size; (void)ws_size;
    const float* latent = (const float*)d_in[0];
    const float* W      = (const float*)d_in[1];
    const float* bvec   = (const float*)d_in[2];
    const float* params = (const float*)d_in[3];
    float* out  = (float*)d_out;
    float* wt   = (float*)d_ws;              // LDIM*NQ floats
    float* ctcs = wt + LDIM * NQ;            // 2*NQ floats

    hipLaunchKernelGGL(qll_prep, dim3((LDIM * NQ + 255) / 256), dim3(256), 0, stream,
                       W, params, wt, ctcs);
    hipLaunchKernelGGL(qll_main, dim3(BATCH / BLK_ROWS), dim3(256), 0, stream,
                       latent, wt, bvec, ctcs, ctcs + NQ, out);
}